// Round 10
// baseline (124.809 us; speedup 1.0000x reference)
//
#include <hip/hip_runtime.h>

// DWN pipeline v10: 320 blocks, block-local bits, 1 chain/wave, local flags.
//
// Evidence: R9 solved traffic (FETCH 4.3MB, WRITE 20KB) but ran 80 blocks ->
// 176 idle CUs, occupancy 13%, VALUBusy 7%: latency-bound on serial
// dependent gather chains (~6.5 per wave). R8 validated relaxed agent-scope
// atomics as a cross-XCD coherence path with no cache maintenance, and the
// cumulative-flag protocol (all-threads base load) as graph-replay-safe.
//
// Structure: grid = 8 row-groups x 40 chunks = 320 blocks x 1024 threads.
//   P1 (per block): stage x 64x128 tiles coalesced -> padded LDS -> column
//       reads (2-way banks, free) -> ballot -> s_bits[3072] u64. 8 iters.
//       idx2 rows for the block's o2s are prefetched BEFORE P1 (latency
//       hides under staging).
//   P23: 25 o2 per block -> each wave owns <=2 full chains (max TLP/MLP).
//       h1 inline: 6 LDS u64 broadcasts + luts1 gather in a uniform 256B
//       row; 6-D fold verbatim. Result -> global h2T[o2*512+row] via
//       relaxed agent atomic stores (R8-validated).
//   P4: blocks with chunk%4==0 (c = chunk/4, 80 reducers) wait on the 3
//       sibling flags (same rg, chunks +1..+3), acquire-fence, then the
//       verbatim two-level 10x10 sum for rows rbase..rbase+63.
// Workers never wait; 80 reducers < 256 CUs -> deadlock impossible; spin
// caps turn any surprise into a wrong answer, not a hang.
// FP order verbatim (bit code, LSB-first fold, 10x10 sum, /3.3333333f).

#define FEAT   1024
#define O2N    1000
#define NCLS   10
#define NRG    8
#define NCHUNK 40
#define CH     25            // o2 per chunk
#define NB     (NCHUNK * NRG)   // 320
#define NT     1024

#define SCOPE_AGENT __HIP_MEMORY_SCOPE_AGENT

// Cumulative flags: +1 per block per launch -> equal at launch boundaries.
__device__ unsigned g_flags[NB];

__global__ __launch_bounds__(NT) void dwn_v10(
    const float* __restrict__ x,       // [512,1024]
    const float* __restrict__ thr,     // [1024,3] == flat [3072]
    const float* __restrict__ luts1,   // [2000,64]
    const int*   __restrict__ idx1,    // [2000,6]
    const float* __restrict__ luts2,   // [1000,64]
    const int*   __restrict__ idx2,    // [1000,6]
    float* __restrict__ out,           // [512,10]
    float* __restrict__ h2T)           // ws: [1000][512]
{
    __shared__ unsigned long long s_bits[FEAT * 3];   // 24 KB
    __shared__ float xt[64][129];                     // 33 KB, padded

    const int t     = threadIdx.x;
    const int lane  = t & 63;
    const int wl    = t >> 6;                // 0..15
    const int bid   = blockIdx.x;
    const int chunk = bid >> 3;              // 0..39
    const int rg    = bid & 7;               // 0..7
    const int rbase = rg << 6;

    // Replay-safe base: ALL threads read own flag (R8-validated fix).
    const unsigned base =
        __hip_atomic_load(&g_flags[bid], __ATOMIC_RELAXED, SCOPE_AGENT);

    // ---- Prefetch this wave's o2 index rows (hides under P1) ----
    const int  o2a  = chunk * CH + wl;            // wl<16 < CH -> always valid
    const bool hasB = (wl + 16) < CH;             // waves 0..8
    const int  o2b  = hasB ? (o2a + 16) : o2a;    // in-bounds alias if absent
    const int2* ipa = (const int2*)(idx2 + o2a * 6);
    const int2 pa0 = ipa[0], pa1 = ipa[1], pa2 = ipa[2];
    const int2* ipb = (const int2*)(idx2 + o2b * 6);
    const int2 pb0 = ipb[0], pb1 = ipb[1], pb2 = ipb[2];

    // ---- P1: thermometer bits for rows rbase..rbase+63 (8 tile iters) ----
    for (int ti = 0; ti < FEAT / 128; ++ti) {
        {   // stage 64 rows x 128 cols, 8 floats (2x float4) per thread
            const int row = t >> 4;              // 0..63
            const int c0  = (t & 15) << 3;       // 0,8,...,120
            const float4* src = (const float4*)(
                x + (size_t)(rbase + row) * FEAT + ti * 128 + c0);
            const float4 a = src[0], b2 = src[1];
            xt[row][c0 + 0] = a.x;  xt[row][c0 + 1] = a.y;
            xt[row][c0 + 2] = a.z;  xt[row][c0 + 3] = a.w;
            xt[row][c0 + 4] = b2.x; xt[row][c0 + 5] = b2.y;
            xt[row][c0 + 6] = b2.z; xt[row][c0 + 7] = b2.w;
        }
        __syncthreads();
#pragma unroll
        for (int cc = 0; cc < 8; ++cc) {         // wave wl: cols wl*8..wl*8+7
            const int col = (wl << 3) + cc;      // wave-uniform
            const float val = xt[lane][col];     // stride-129: 2-way, free
            const int f = ti * 128 + col;
            const float* tp = thr + (size_t)f * 3;   // uniform -> s_load
#pragma unroll
            for (int j = 0; j < 3; ++j) {
                const unsigned long long m = __ballot(val > tp[j]);
                if (lane == 0) s_bits[f * 3 + j] = m;
            }
        }
        __syncthreads();
    }

    // ---- P23: up to 2 o2 chains per wave ----
#pragma unroll
    for (int which = 0; which < 2; ++which) {
        if (which == 1 && !hasB) break;
        const int o2 = which ? o2b : o2a;
        const int2 p0 = which ? pb0 : pa0;
        const int2 p1 = which ? pb1 : pa1;
        const int2 p2 = which ? pb2 : pa2;

        float xv[6];
        const int o1s[6] = {p0.x, p0.y, p1.x, p1.y, p2.x, p2.y};
#pragma unroll
        for (int k = 0; k < 6; ++k) {
            const int o1 = o1s[k];
            const int2* iq = (const int2*)(idx1 + o1 * 6);  // wave-uniform
            const int2 q0 = iq[0], q1 = iq[1], q2 = iq[2];
            const int b0 = (int)((s_bits[q0.x] >> lane) & 1ull);
            const int b1 = (int)((s_bits[q0.y] >> lane) & 1ull);
            const int b2 = (int)((s_bits[q1.x] >> lane) & 1ull);
            const int b3 = (int)((s_bits[q1.y] >> lane) & 1ull);
            const int b4 = (int)((s_bits[q2.x] >> lane) & 1ull);
            const int b5 = (int)((s_bits[q2.y] >> lane) & 1ull);
            const int code = (b0 << 5) | (b1 << 4) | (b2 << 3)
                           | (b3 << 2) | (b4 << 1) | b5;
            xv[k] = luts1[o1 * 64 + code];       // uniform 256B row gather
        }

        const float4* lp = (const float4*)(luts2 + (size_t)o2 * 64); // uniform
        float v[16];
#pragma unroll
        for (int q = 0; q < 16; ++q) {           // fold x5 (bit0), x4 (bit1)
            float4 e = lp[q];
            float u0 = e.x + xv[5] * (e.y - e.x);
            float u1 = e.z + xv[5] * (e.w - e.z);
            v[q] = u0 + xv[4] * (u1 - u0);
        }
#pragma unroll
        for (int q = 0; q < 8; ++q) v[q] = v[2*q] + xv[3] * (v[2*q+1] - v[2*q]);
#pragma unroll
        for (int q = 0; q < 4; ++q) v[q] = v[2*q] + xv[2] * (v[2*q+1] - v[2*q]);
#pragma unroll
        for (int q = 0; q < 2; ++q) v[q] = v[2*q] + xv[1] * (v[2*q+1] - v[2*q]);
        const float h2 = v[0] + xv[0] * (v[1] - v[0]);

        // R8-validated write-through: cross-XCD visible, no wbl2/inv.
        __hip_atomic_store(&h2T[(size_t)o2 * 512 + rbase + lane], h2,
                           __ATOMIC_RELAXED, SCOPE_AGENT);
    }

    // ---- Publish: drain block stores, release own flag ----
    __syncthreads();
    if (t == 0)
        __hip_atomic_store(&g_flags[bid], base + 1u, __ATOMIC_RELEASE, SCOPE_AGENT);

    // Workers done; reducers (chunk%4==0) continue.
    if ((chunk & 3) != 0) return;

    // ---- P4 (wave 0 only): wait on 3 sibling flags, then exact sum ----
    if (t < 64) {
        const unsigned target = base + 1u;       // uniform (base loaded by all)
        for (int spin = 0; spin < (1 << 20); ++spin) {
            const unsigned f1 = __hip_atomic_load(&g_flags[bid + 8],
                                                  __ATOMIC_RELAXED, SCOPE_AGENT);
            const unsigned f2 = __hip_atomic_load(&g_flags[bid + 16],
                                                  __ATOMIC_RELAXED, SCOPE_AGENT);
            const unsigned f3 = __hip_atomic_load(&g_flags[bid + 24],
                                                  __ATOMIC_RELAXED, SCOPE_AGENT);
            if (f1 >= target && f2 >= target && f3 >= target) break;
            __builtin_amdgcn_s_sleep(8);
        }
        __builtin_amdgcn_fence(__ATOMIC_ACQUIRE, "agent");

        const int c = chunk >> 2;                // class 0..9
        float s = 0.0f;
#pragma unroll
        for (int p = 0; p < 10; ++p) {
            float s2 = 0.0f;
#pragma unroll
            for (int j = 0; j < 10; ++j) {
                const float hv = __hip_atomic_load(
                    &h2T[(size_t)(c * 100 + p * 10 + j) * 512 + rbase + lane],
                    __ATOMIC_RELAXED, SCOPE_AGENT);
                s2 += hv;
            }
            s += s2;
        }
        out[(size_t)(rbase + lane) * NCLS + c] = s / 3.3333333f;
    }
}

extern "C" void kernel_launch(void* const* d_in, const int* in_sizes, int n_in,
                              void* d_out, int out_size, void* d_ws, size_t ws_size,
                              hipStream_t stream) {
    const float* x     = (const float*)d_in[0];
    const float* thr   = (const float*)d_in[1];
    const float* luts1 = (const float*)d_in[2];
    const int*   idx1  = (const int*)  d_in[3];
    const float* luts2 = (const float*)d_in[4];
    const int*   idx2  = (const int*)  d_in[5];
    float* out = (float*)d_out;
    float* h2T = (float*)d_ws;         // 2 MB workspace

    dwn_v10<<<NB, NT, 0, stream>>>(x, thr, luts1, idx1, luts2, idx2, out, h2T);
}

// Round 11
// 97.575 us; speedup vs baseline: 1.2791x; 1.2791x over previous
//
#include <hip/hip_runtime.h>

// DWN pipeline: ONE dispatch, R4's transposed 4-phase structure, with
// FENCE-FREE grid barriers (no wbl2/inv anywhere).
//
// Evidence: R4 measured the transposed phases at ~7us total and 13us per
// fenced barrier (agent release/acquire = L2 writeback+invalidate through a
// poison-dirtied L2). R7/R8 validated that relaxed agent-scope atomics
// (write-through to the coherent point) move data cross-XCD correctly with
// NO cache maintenance, and that cumulative flags + all-thread base load is
// graph-replay-safe. R9/R10 showed the block-local-everything alternative
// is stuck at 60-67us regardless of block count.
//
// Protocol: all cross-block data (bitsT u64, h1T f32, h2T f32) uses RELAXED
// agent atomics for both store and load. Barrier arrival = __syncthreads()
// (drains vmcnt -> write-through stores are at the coherent point) + relaxed
// own-flag store. Detection = per-block wave-0 scan of all 256 flags with
// relaxed loads. Waves issue in order, and post-barrier data loads go to the
// coherent point -> freshness needs no acquire fence. Barrier 3 is detected
// only by the 5 P4 blocks; spin caps turn surprises into wrong answers, not
// hangs. Phase bodies verbatim from the R3/R4-verified kernel -> absmax 0.
//
//   P1: thermometer encode -> transposed bit-pack  bitsT[3072][8] u64
//   P2: layer 1 (pure 6-bit LUT)                   h1T[2000][512] f32
//   P3: layer 2 (6-D multilinear, LSB-first fold)  h2T[1000][512] f32
//   P4: group-sum / tau (exact 10x10 two-level)    out[512][10]

#define FEAT   1024
#define O1     2000
#define O2     1000
#define NCLS   10
#define NB     256
#define NT     1024
#define NWAVES (NB * (NT / 64))   // 4096 global waves

#define WS_BITS_OFF  0
#define WS_H1_OFF    (256 << 10)                 // 256 KB
#define WS_H2_OFF    ((256 << 10) + (4 << 20))   // 256 KB + 4 MB

#define SCOPE_AGENT __HIP_MEMORY_SCOPE_AGENT

// Cumulative flags: +3 per block per launch -> all equal at launch
// boundaries; zero-init at module load; replay-safe.
__device__ unsigned g_flags[NB];

__global__ __launch_bounds__(NT, 4) void dwn_ffb(
    const float* __restrict__ x,       // [512,1024]
    const float* __restrict__ thr,     // [1024,3] == flat [3072]
    const float* __restrict__ luts1,   // [2000,64]
    const int*   __restrict__ idx1,    // [2000,6] in [0,3072)
    const float* __restrict__ luts2,   // [1000,64]
    const int*   __restrict__ idx2,    // [1000,6] in [0,2000)
    float* __restrict__ out,           // [512,10]
    unsigned long long* __restrict__ bitsT,  // [3072][8]
    float* __restrict__ h1T,                 // [2000][512]
    float* __restrict__ h2T)                 // [1000][512]
{
    const int t    = threadIdx.x;
    const int lane = t & 63;
    const int wl   = t >> 6;                 // wave in block, 0..15
    const int b    = blockIdx.x;
    const int gw   = (b << 4) | wl;          // global wave id, 0..4095

    // Replay-safe base: ALL threads read the block's own flag (R8 fix).
    const unsigned base =
        __hip_atomic_load(&g_flags[b], __ATOMIC_RELAXED, SCOPE_AGENT);

    // ---- P1: thermometer encode + transposed bit-pack (R3 verbatim) ----
    // Waves 0..7: rows 0..511 for features {4b,4b+1};
    // waves 8..15: same rows for features {4b+2,4b+3}.
    {
        const int w8    = wl & 7;
        const int row   = (w8 << 6) | lane;
        const int fbase = (b << 2) | ((wl >> 3) << 1);
#pragma unroll
        for (int ff = 0; ff < 2; ++ff) {
            const int f = fbase + ff;
            const float xv = x[(size_t)row * FEAT + f];
            const float* tp = thr + (size_t)f * 3;   // wave-uniform
#pragma unroll
            for (int j = 0; j < 3; ++j) {
                const unsigned long long m = __ballot(xv > tp[j]);
                if (lane == 0)
                    __hip_atomic_store(&bitsT[(size_t)(f * 3 + j) * 8 + w8],
                                       m, __ATOMIC_RELAXED, SCOPE_AGENT);
            }
        }
    }

    // ---- fence-free barrier #1 ----
    __syncthreads();                         // drains vmcnt for all waves
    if (t == 0)
        __hip_atomic_store(&g_flags[b], base + 1u, __ATOMIC_RELAXED, SCOPE_AGENT);
    if (t < 64) {
        for (int spin = 0; spin < (1 << 20); ++spin) {
            const unsigned v0 = __hip_atomic_load(&g_flags[t],       __ATOMIC_RELAXED, SCOPE_AGENT);
            const unsigned v1 = __hip_atomic_load(&g_flags[t + 64],  __ATOMIC_RELAXED, SCOPE_AGENT);
            const unsigned v2 = __hip_atomic_load(&g_flags[t + 128], __ATOMIC_RELAXED, SCOPE_AGENT);
            const unsigned v3 = __hip_atomic_load(&g_flags[t + 192], __ATOMIC_RELAXED, SCOPE_AGENT);
            const unsigned tg = base + 1u;
            if (__all((v0 >= tg) & (v1 >= tg) & (v2 >= tg) & (v3 >= tg))) break;
            __builtin_amdgcn_s_sleep(2);
        }
    }
    __syncthreads();

    // ---- P2: layer 1 — pure 6-bit table lookup (R3 verbatim) ----
    for (int task = gw; task < O1 * 8; task += NWAVES) {
        const int o = task >> 3;
        const int w = task & 7;
        const int* ip = idx1 + o * 6;        // wave-uniform, read-only input

        const unsigned long long m0 = __hip_atomic_load(&bitsT[(size_t)ip[0] * 8 + w], __ATOMIC_RELAXED, SCOPE_AGENT);
        const unsigned long long m1 = __hip_atomic_load(&bitsT[(size_t)ip[1] * 8 + w], __ATOMIC_RELAXED, SCOPE_AGENT);
        const unsigned long long m2 = __hip_atomic_load(&bitsT[(size_t)ip[2] * 8 + w], __ATOMIC_RELAXED, SCOPE_AGENT);
        const unsigned long long m3 = __hip_atomic_load(&bitsT[(size_t)ip[3] * 8 + w], __ATOMIC_RELAXED, SCOPE_AGENT);
        const unsigned long long m4 = __hip_atomic_load(&bitsT[(size_t)ip[4] * 8 + w], __ATOMIC_RELAXED, SCOPE_AGENT);
        const unsigned long long m5 = __hip_atomic_load(&bitsT[(size_t)ip[5] * 8 + w], __ATOMIC_RELAXED, SCOPE_AGENT);

        const int code = ((int)((m0 >> lane) & 1ull) << 5)
                       | ((int)((m1 >> lane) & 1ull) << 4)
                       | ((int)((m2 >> lane) & 1ull) << 3)
                       | ((int)((m3 >> lane) & 1ull) << 2)
                       | ((int)((m4 >> lane) & 1ull) << 1)
                       |  (int)((m5 >> lane) & 1ull);

        __hip_atomic_store(&h1T[(size_t)o * 512 + (w << 6) + lane],
                           luts1[o * 64 + code], __ATOMIC_RELAXED, SCOPE_AGENT);
    }

    // ---- fence-free barrier #2 ----
    __syncthreads();
    if (t == 0)
        __hip_atomic_store(&g_flags[b], base + 2u, __ATOMIC_RELAXED, SCOPE_AGENT);
    if (t < 64) {
        for (int spin = 0; spin < (1 << 20); ++spin) {
            const unsigned v0 = __hip_atomic_load(&g_flags[t],       __ATOMIC_RELAXED, SCOPE_AGENT);
            const unsigned v1 = __hip_atomic_load(&g_flags[t + 64],  __ATOMIC_RELAXED, SCOPE_AGENT);
            const unsigned v2 = __hip_atomic_load(&g_flags[t + 128], __ATOMIC_RELAXED, SCOPE_AGENT);
            const unsigned v3 = __hip_atomic_load(&g_flags[t + 192], __ATOMIC_RELAXED, SCOPE_AGENT);
            const unsigned tg = base + 2u;
            if (__all((v0 >= tg) & (v1 >= tg) & (v2 >= tg) & (v3 >= tg))) break;
            __builtin_amdgcn_s_sleep(2);
        }
    }
    __syncthreads();

    // ---- P3: layer 2 — 6-D multilinear, LSB-first fold (R3 verbatim) ----
    for (int task = gw; task < O2 * 8; task += NWAVES) {
        const int o  = task >> 3;
        const int rr = ((task & 7) << 6) | lane;
        const int* ip = idx2 + o * 6;        // wave-uniform, read-only input

        const float xv0 = __hip_atomic_load(&h1T[(size_t)ip[0] * 512 + rr], __ATOMIC_RELAXED, SCOPE_AGENT);
        const float xv1 = __hip_atomic_load(&h1T[(size_t)ip[1] * 512 + rr], __ATOMIC_RELAXED, SCOPE_AGENT);
        const float xv2 = __hip_atomic_load(&h1T[(size_t)ip[2] * 512 + rr], __ATOMIC_RELAXED, SCOPE_AGENT);
        const float xv3 = __hip_atomic_load(&h1T[(size_t)ip[3] * 512 + rr], __ATOMIC_RELAXED, SCOPE_AGENT);
        const float xv4 = __hip_atomic_load(&h1T[(size_t)ip[4] * 512 + rr], __ATOMIC_RELAXED, SCOPE_AGENT);
        const float xv5 = __hip_atomic_load(&h1T[(size_t)ip[5] * 512 + rr], __ATOMIC_RELAXED, SCOPE_AGENT);

        const float4* lp = (const float4*)(luts2 + (size_t)o * 64);  // uniform row
        float v[16];
#pragma unroll
        for (int q = 0; q < 16; ++q) {       // fold x5 (bit0), x4 (bit1)
            float4 e = lp[q];
            float u0 = e.x + xv5 * (e.y - e.x);
            float u1 = e.z + xv5 * (e.w - e.z);
            v[q] = u0 + xv4 * (u1 - u0);
        }
#pragma unroll
        for (int q = 0; q < 8; ++q) v[q] = v[2*q] + xv3 * (v[2*q+1] - v[2*q]);
#pragma unroll
        for (int q = 0; q < 4; ++q) v[q] = v[2*q] + xv2 * (v[2*q+1] - v[2*q]);
#pragma unroll
        for (int q = 0; q < 2; ++q) v[q] = v[2*q] + xv1 * (v[2*q+1] - v[2*q]);
        __hip_atomic_store(&h2T[(size_t)o * 512 + rr],
                           v[0] + xv0 * (v[1] - v[0]),
                           __ATOMIC_RELAXED, SCOPE_AGENT);
    }

    // ---- fence-free barrier #3 (arrival by all; detection only by P4 blocks) ----
    __syncthreads();
    if (t == 0)
        __hip_atomic_store(&g_flags[b], base + 3u, __ATOMIC_RELAXED, SCOPE_AGENT);
    if (b >= (NCLS * 8 + 15) / 16) return;   // blocks 5..255 done
    if (t < 64) {
        for (int spin = 0; spin < (1 << 20); ++spin) {
            const unsigned v0 = __hip_atomic_load(&g_flags[t],       __ATOMIC_RELAXED, SCOPE_AGENT);
            const unsigned v1 = __hip_atomic_load(&g_flags[t + 64],  __ATOMIC_RELAXED, SCOPE_AGENT);
            const unsigned v2 = __hip_atomic_load(&g_flags[t + 128], __ATOMIC_RELAXED, SCOPE_AGENT);
            const unsigned v3 = __hip_atomic_load(&g_flags[t + 192], __ATOMIC_RELAXED, SCOPE_AGENT);
            const unsigned tg = base + 3u;
            if (__all((v0 >= tg) & (v1 >= tg) & (v2 >= tg) & (v3 >= tg))) break;
            __builtin_amdgcn_s_sleep(2);
        }
    }
    __syncthreads();

    // ---- P4: group sum / tau, exact 10x10 two-level order (R3 verbatim) ----
    if (gw < NCLS * 8) {
        const int c  = gw >> 3;
        const int rr = ((gw & 7) << 6) | lane;
        float s = 0.0f;
#pragma unroll
        for (int p = 0; p < 10; ++p) {
            float s2 = 0.0f;
#pragma unroll
            for (int j = 0; j < 10; ++j) {
                const float hv = __hip_atomic_load(
                    &h2T[(size_t)(c * 100 + p * 10 + j) * 512 + rr],
                    __ATOMIC_RELAXED, SCOPE_AGENT);
                s2 += hv;
            }
            s += s2;
        }
        out[(size_t)rr * NCLS + c] = s / 3.3333333f;
    }
}

extern "C" void kernel_launch(void* const* d_in, const int* in_sizes, int n_in,
                              void* d_out, int out_size, void* d_ws, size_t ws_size,
                              hipStream_t stream) {
    const float* x     = (const float*)d_in[0];
    const float* thr   = (const float*)d_in[1];
    const float* luts1 = (const float*)d_in[2];
    const int*   idx1  = (const int*)  d_in[3];
    const float* luts2 = (const float*)d_in[4];
    const int*   idx2  = (const int*)  d_in[5];
    float* out = (float*)d_out;

    char* ws = (char*)d_ws;
    unsigned long long* bitsT = (unsigned long long*)(ws + WS_BITS_OFF);
    float* h1T = (float*)(ws + WS_H1_OFF);
    float* h2T = (float*)(ws + WS_H2_OFF);

    dwn_ffb<<<NB, NT, 0, stream>>>(x, thr, luts1, idx1, luts2, idx2,
                                   out, bitsT, h1T, h2T);
}